// Round 3
// baseline (16164.066 us; speedup 1.0000x reference)
//
#include <hip/hip_runtime.h>
#include <hip/hip_bf16.h>

#define NU_ 50000
#define NI_ 50000
#define NN  (NU_ + NI_)   // 100000
#define DD  64
#define KK  4
#define EE  1000000

// ---------- degree count (per-occurrence, matches segment_sum of ones) ----------
__global__ void k_deg(const int* __restrict__ r, const int* __restrict__ c,
                      float* __restrict__ deg) {
    int e = blockIdx.x * blockDim.x + threadIdx.x;
    if (e >= EE) return;
    int a = r[e], b = c[e];
    if ((unsigned)a >= (unsigned)NU_ || (unsigned)b >= (unsigned)NI_) return; // defensive
    unsafeAtomicAdd(&deg[a], 1.0f);
    unsafeAtomicAdd(&deg[NU_ + b], 1.0f);
}

// ---------- deg -> dinv = (deg + 1e-7)^-0.5, in place ----------
__global__ void k_dinv(float* __restrict__ deg) {
    int i = blockIdx.x * blockDim.x + threadIdx.x;
    if (i < NN) deg[i] = rsqrtf(deg[i] + 1e-7f);
}

// ---------- h = relu(x) + bias (fp32) ----------
__global__ void k_h(const float* __restrict__ x, const float* __restrict__ bias,
                    float* __restrict__ h) {
    int i = blockIdx.x * blockDim.x + threadIdx.x;
    if (i < NN * DD) {
        h[i] = fmaxf(x[i], 0.0f) + bias[i & 63];
    }
}

// ---------- symmetric SpMM: out[src] += val * in[dst], both directions ----------
// 16 threads/edge, float4 per thread (coalesced 256B row segments).
__global__ void k_spmm(const int* __restrict__ r, const int* __restrict__ c,
                       const float* __restrict__ dinv, const float* __restrict__ hin,
                       float* __restrict__ out) {
    long long t = (long long)blockIdx.x * blockDim.x + threadIdx.x;
    int e = (int)(t >> 4);
    if (e >= EE) return;
    int q = ((int)t & 15) << 2;            // column offset 0..60
    int a = r[e], b = c[e];
    if ((unsigned)a >= (unsigned)NU_ || (unsigned)b >= (unsigned)NI_) return; // defensive
    b += NU_;
    float val = dinv[a] * dinv[b];
    const float4 ha = *(const float4*)(hin + (size_t)a * DD + q);
    const float4 hb = *(const float4*)(hin + (size_t)b * DD + q);
    float* oa = out + (size_t)a * DD + q;
    float* ob = out + (size_t)b * DD + q;
    unsafeAtomicAdd(oa + 0, val * hb.x);
    unsafeAtomicAdd(oa + 1, val * hb.y);
    unsafeAtomicAdd(oa + 2, val * hb.z);
    unsafeAtomicAdd(oa + 3, val * hb.w);
    unsafeAtomicAdd(ob + 0, val * ha.x);
    unsafeAtomicAdd(ob + 1, val * ha.y);
    unsafeAtomicAdd(ob + 2, val * ha.z);
    unsafeAtomicAdd(ob + 3, val * ha.w);
}

// ---------- fused: softmax(node) -> fc1 -> fusion gate -> x_new ----------
// one wave per row; cross-lane via __shfl (race-free); weights transposed in LDS.
// Runs IN PLACE: node and out_nodes may alias (each thread reads only its own
// element before writing it).
__global__ __launch_bounds__(256) void k_row(
    const float* __restrict__ node, const float* __restrict__ xsrc,
    const float* __restrict__ fc1W, const float* __restrict__ fusW,
    const float* __restrict__ l1b, const float* __restrict__ l2w,
    const float* __restrict__ l2b, float* __restrict__ out_nodes) {
    __shared__ float sFc[DD * DD];   // sFc[d*64+j] = fc1W[j][d]
    __shared__ float sFu[DD * DD];   // sFu[d*64+j] = fusW[j][d]
    __shared__ float sB1[DD];
    __shared__ float sL2[DD];
    __shared__ float sB2;

    for (int idx = threadIdx.x; idx < DD * DD; idx += 256) {
        int j = idx >> 6, d = idx & 63;
        sFc[d * DD + j] = fc1W[idx];
        sFu[d * DD + j] = fusW[idx];
    }
    if (threadIdx.x < DD) {
        sB1[threadIdx.x] = l1b[threadIdx.x];
        sL2[threadIdx.x] = l2w[threadIdx.x];
    }
    if (threadIdx.x == 0) sB2 = l2b[0];
    __syncthreads();

    const int wave = threadIdx.x >> 6;
    const int lane = threadIdx.x & 63;

    for (int row = blockIdx.x * 4 + wave; row < NN; row += gridDim.x * 4) {
        const size_t base = (size_t)row * DD + lane;
        float v = node[base];
        // --- softmax over D=64 ---
        float m = v;
        #pragma unroll
        for (int s = 1; s < 64; s <<= 1) m = fmaxf(m, __shfl_xor(m, s));
        float ev = __expf(v - m);
        float sum = ev;
        #pragma unroll
        for (int s = 1; s < 64; s <<= 1) sum += __shfl_xor(sum, s);
        float sm = ev / sum;
        // --- fc1: nf[lane] = sum_d sm[d] * fc1W[lane][d] ---
        float nf = 0.0f;
        #pragma unroll
        for (int d = 0; d < DD; d++) nf = fmaf(__shfl(sm, d), sFc[d * DD + lane], nf);
        float xc = xsrc[base];
        // --- fusion branch: xc ---
        float acc = 0.0f;
        #pragma unroll
        for (int d = 0; d < DD; d++) acc = fmaf(__shfl(xc, d), sFu[d * DD + lane], acc);
        float tt = tanhf(acc + sB1[lane]);
        float p = tt * sL2[lane];
        #pragma unroll
        for (int s = 1; s < 64; s <<= 1) p += __shfl_xor(p, s);
        float s_x = p + sB2;
        // --- fusion branch: nf ---
        acc = 0.0f;
        #pragma unroll
        for (int d = 0; d < DD; d++) acc = fmaf(__shfl(nf, d), sFu[d * DD + lane], acc);
        tt = tanhf(acc + sB1[lane]);
        p = tt * sL2[lane];
        #pragma unroll
        for (int s = 1; s < 64; s <<= 1) p += __shfl_xor(p, s);
        float s_n = p + sB2;
        // --- 2-way softmax gate + blend ---
        float mm = fmaxf(s_x, s_n);
        float e0 = __expf(s_x - mm), e1 = __expf(s_n - mm);
        float inv = 1.0f / (e0 + e1);
        float xn = (e0 * xc + e1 * nf) * inv;
        out_nodes[base] = xn;
    }
}

extern "C" void kernel_launch(void* const* d_in, const int* in_sizes, int n_in,
                              void* d_out, int out_size, void* d_ws, size_t ws_size,
                              hipStream_t stream) {
    const float* x    = (const float*)d_in[0];
    const float* b1   = (const float*)d_in[1];  // hgc1_bias
    const float* fc1W = (const float*)d_in[2];
    const float* fusW = (const float*)d_in[3];  // fus_l1_W
    const float* l1b  = (const float*)d_in[4];
    const float* l2w  = (const float*)d_in[5];
    const float* l2b  = (const float*)d_in[6];
    const int* rows = (const int*)d_in[7];
    const int* cols = (const int*)d_in[8];
    float* out = (float*)d_out;

    const int ND = NN * DD;  // 6,400,000
    // workspace: ONLY deg (0.4 MB) — everything else lives in d_out slots.
    float* deg = (float*)d_ws;

    for (int k = 0; k < KK; k++) {
        const int* r = rows + (size_t)k * EE;
        const int* c = cols + (size_t)k * EE;
        const float* xk = (k == 0) ? x : out + (size_t)(k - 1) * ND;  // carry
        float* out_n = out + (size_t)k * ND;         // nodes[k] slot (h stage -> node acc -> x_new)
        float* out_e = out + (size_t)(KK + k) * ND;  // edges[k] slot (edge acc -> final)

        // degree -> dinv
        hipMemsetAsync(deg, 0, NN * sizeof(float), stream);
        k_deg<<<(EE + 255) / 256, 256, 0, stream>>>(r, c, deg);
        k_dinv<<<(NN + 255) / 256, 256, 0, stream>>>(deg);

        // h = relu(xk)+bias, staged in nodes[k] slot
        k_h<<<(ND + 255) / 256, 256, 0, stream>>>(xk, b1, out_n);

        // edge = L h  -> accumulate directly into edges[k] output slot
        hipMemsetAsync(out_e, 0, (size_t)ND * sizeof(float), stream);
        k_spmm<<<(int)(((long long)EE * 16 + 255) / 256), 256, 0, stream>>>(r, c, deg, out_n, out_e);

        // node = L edge -> accumulate into nodes[k] slot (h is dead)
        hipMemsetAsync(out_n, 0, (size_t)ND * sizeof(float), stream);
        k_spmm<<<(int)(((long long)EE * 16 + 255) / 256), 256, 0, stream>>>(r, c, deg, out_e, out_n);

        // softmax -> fc1 -> fusion gate; x_new written in place into nodes[k]
        k_row<<<2048, 256, 0, stream>>>(out_n, xk, fc1W, fusW, l1b, l2w, l2b, out_n);
    }
}

// Round 4
// 5188.284 us; speedup vs baseline: 3.1155x; 3.1155x over previous
//
#include <hip/hip_runtime.h>
#include <hip/hip_bf16.h>

#define NU_ 50000
#define NI_ 50000
#define NN  (NU_ + NI_)   // 100000
#define DD  64
#define KK  4
#define EE  1000000

// ---------- histogram of node degrees (int counts) ----------
__global__ void k_hist(const int* __restrict__ r, const int* __restrict__ c,
                       int* __restrict__ cnt) {
    int e = blockIdx.x * blockDim.x + threadIdx.x;
    if (e >= EE) return;
    int a = r[e], b = c[e];
    if ((unsigned)a >= (unsigned)NU_ || (unsigned)b >= (unsigned)NI_) return; // defensive
    atomicAdd(&cnt[a], 1);
    atomicAdd(&cnt[NU_ + b], 1);
}

// ---------- single-block exclusive scan of cnt -> row_ptr, cursor; dinv ----------
__global__ __launch_bounds__(1024) void k_scan(const int* __restrict__ cnt,
                                               int* __restrict__ row_ptr,
                                               int* __restrict__ cursor,
                                               float* __restrict__ dinv) {
    __shared__ int sums[1024];
    const int tid = threadIdx.x;
    const int CH = (NN + 1023) / 1024;  // 98
    int begin = tid * CH;
    int end = begin + CH; if (end > NN) end = NN;
    int s = 0;
    for (int i = begin; i < end; i++) s += cnt[i];
    sums[tid] = s;
    __syncthreads();
    // inclusive scan over 1024 partials
    for (int off = 1; off < 1024; off <<= 1) {
        int v = (tid >= off) ? sums[tid - off] : 0;
        __syncthreads();
        sums[tid] += v;
        __syncthreads();
    }
    int prefix = (tid > 0) ? sums[tid - 1] : 0;
    for (int i = begin; i < end; i++) {
        row_ptr[i] = prefix;
        cursor[i] = prefix;
        dinv[i] = rsqrtf((float)cnt[i] + 1e-7f);
        prefix += cnt[i];
    }
    if (tid == 1023) row_ptr[NN] = sums[1023];
}

// ---------- scatter edges into CSR adjacency (both directions) ----------
__global__ void k_scatter(const int* __restrict__ r, const int* __restrict__ c,
                          int* __restrict__ cursor, int* __restrict__ adj) {
    int e = blockIdx.x * blockDim.x + threadIdx.x;
    if (e >= EE) return;
    int a = r[e], b = c[e];
    if ((unsigned)a >= (unsigned)NU_ || (unsigned)b >= (unsigned)NI_) return; // defensive
    b += NU_;
    int p = atomicAdd(&cursor[a], 1);
    adj[p] = b;
    int q = atomicAdd(&cursor[b], 1);
    adj[q] = a;
}

// ---------- h = relu(x) + bias (fp32) ----------
__global__ void k_h(const float* __restrict__ x, const float* __restrict__ bias,
                    float* __restrict__ h) {
    int i = blockIdx.x * blockDim.x + threadIdx.x;
    if (i < NN * DD) {
        h[i] = fmaxf(x[i], 0.0f) + bias[i & 63];
    }
}

// ---------- pull-based SpMM: out[row] = dinv[row] * sum_nbr dinv[nbr]*hin[nbr] ----------
// one wave per row, lane = column; coalesced 256B row gathers, zero atomics.
__global__ __launch_bounds__(256) void k_pull(const int* __restrict__ row_ptr,
                                              const int* __restrict__ adj,
                                              const float* __restrict__ dinv,
                                              const float* __restrict__ hin,
                                              float* __restrict__ out) {
    const int wave = threadIdx.x >> 6;
    const int lane = threadIdx.x & 63;
    const int row = blockIdx.x * 4 + wave;
    if (row >= NN) return;
    const int start = row_ptr[row];
    const int end = row_ptr[row + 1];
    float acc = 0.0f;
    for (int base = start; base < end; base += 64) {
        int n = end - base; if (n > 64) n = 64;
        int idx = (lane < n) ? adj[base + lane] : 0;
        float dn = (lane < n) ? dinv[idx] : 0.0f;
        for (int j = 0; j < n; j++) {
            int nbr = __shfl(idx, j);
            float w = __shfl(dn, j);
            acc = fmaf(w, hin[(size_t)nbr * DD + lane], acc);
        }
    }
    out[(size_t)row * DD + lane] = dinv[row] * acc;
}

// ---------- fused: softmax(node) -> fc1 -> fusion gate -> x_new ----------
// one wave per row; cross-lane via __shfl; weights transposed in LDS.
// Runs IN PLACE (node may alias out_nodes).
__global__ __launch_bounds__(256) void k_row(
    const float* __restrict__ node, const float* __restrict__ xsrc,
    const float* __restrict__ fc1W, const float* __restrict__ fusW,
    const float* __restrict__ l1b, const float* __restrict__ l2w,
    const float* __restrict__ l2b, float* __restrict__ out_nodes) {
    __shared__ float sFc[DD * DD];   // sFc[d*64+j] = fc1W[j][d]
    __shared__ float sFu[DD * DD];   // sFu[d*64+j] = fusW[j][d]
    __shared__ float sB1[DD];
    __shared__ float sL2[DD];
    __shared__ float sB2;

    for (int idx = threadIdx.x; idx < DD * DD; idx += 256) {
        int j = idx >> 6, d = idx & 63;
        sFc[d * DD + j] = fc1W[idx];
        sFu[d * DD + j] = fusW[idx];
    }
    if (threadIdx.x < DD) {
        sB1[threadIdx.x] = l1b[threadIdx.x];
        sL2[threadIdx.x] = l2w[threadIdx.x];
    }
    if (threadIdx.x == 0) sB2 = l2b[0];
    __syncthreads();

    const int wave = threadIdx.x >> 6;
    const int lane = threadIdx.x & 63;

    for (int row = blockIdx.x * 4 + wave; row < NN; row += gridDim.x * 4) {
        const size_t base = (size_t)row * DD + lane;
        float v = node[base];
        // --- softmax over D=64 ---
        float m = v;
        #pragma unroll
        for (int s = 1; s < 64; s <<= 1) m = fmaxf(m, __shfl_xor(m, s));
        float ev = __expf(v - m);
        float sum = ev;
        #pragma unroll
        for (int s = 1; s < 64; s <<= 1) sum += __shfl_xor(sum, s);
        float sm = ev / sum;
        // --- fc1 ---
        float nf = 0.0f;
        #pragma unroll
        for (int d = 0; d < DD; d++) nf = fmaf(__shfl(sm, d), sFc[d * DD + lane], nf);
        float xc = xsrc[base];
        // --- fusion branch: xc ---
        float acc = 0.0f;
        #pragma unroll
        for (int d = 0; d < DD; d++) acc = fmaf(__shfl(xc, d), sFu[d * DD + lane], acc);
        float tt = tanhf(acc + sB1[lane]);
        float p = tt * sL2[lane];
        #pragma unroll
        for (int s = 1; s < 64; s <<= 1) p += __shfl_xor(p, s);
        float s_x = p + sB2;
        // --- fusion branch: nf ---
        acc = 0.0f;
        #pragma unroll
        for (int d = 0; d < DD; d++) acc = fmaf(__shfl(nf, d), sFu[d * DD + lane], acc);
        tt = tanhf(acc + sB1[lane]);
        p = tt * sL2[lane];
        #pragma unroll
        for (int s = 1; s < 64; s <<= 1) p += __shfl_xor(p, s);
        float s_n = p + sB2;
        // --- gate + blend ---
        float mm = fmaxf(s_x, s_n);
        float e0 = __expf(s_x - mm), e1 = __expf(s_n - mm);
        float inv = 1.0f / (e0 + e1);
        float xn = (e0 * xc + e1 * nf) * inv;
        out_nodes[base] = xn;
    }
}

extern "C" void kernel_launch(void* const* d_in, const int* in_sizes, int n_in,
                              void* d_out, int out_size, void* d_ws, size_t ws_size,
                              hipStream_t stream) {
    const float* x    = (const float*)d_in[0];
    const float* b1   = (const float*)d_in[1];  // hgc1_bias
    const float* fc1W = (const float*)d_in[2];
    const float* fusW = (const float*)d_in[3];  // fus_l1_W
    const float* l1b  = (const float*)d_in[4];
    const float* l2w  = (const float*)d_in[5];
    const float* l2b  = (const float*)d_in[6];
    const int* rows = (const int*)d_in[7];
    const int* cols = (const int*)d_in[8];
    float* out = (float*)d_out;

    const int ND = NN * DD;  // 6,400,000

    // workspace layout (~9.7 MB)
    float* dinv    = (float*)d_ws;           // NN
    int*   cnt     = (int*)(dinv + NN);      // NN
    int*   row_ptr = cnt + NN;               // NN+1
    int*   cursor  = row_ptr + NN + 1;       // NN
    int*   adj     = cursor + NN;            // 2*EE

    for (int k = 0; k < KK; k++) {
        const int* r = rows + (size_t)k * EE;
        const int* c = cols + (size_t)k * EE;
        const float* xk = (k == 0) ? x : out + (size_t)(k - 1) * ND;  // carry
        float* out_n = out + (size_t)k * ND;         // nodes[k] slot
        float* out_e = out + (size_t)(KK + k) * ND;  // edges[k] slot

        // --- CSR build ---
        hipMemsetAsync(cnt, 0, NN * sizeof(int), stream);
        k_hist<<<(EE + 255) / 256, 256, 0, stream>>>(r, c, cnt);
        k_scan<<<1, 1024, 0, stream>>>(cnt, row_ptr, cursor, dinv);
        k_scatter<<<(EE + 255) / 256, 256, 0, stream>>>(r, c, cursor, adj);

        // h = relu(xk)+bias, staged in nodes[k] slot
        k_h<<<(ND + 255) / 256, 256, 0, stream>>>(xk, b1, out_n);

        // edge = L h  (pull, direct store into edges[k] output)
        k_pull<<<(NN + 3) / 4, 256, 0, stream>>>(row_ptr, adj, dinv, out_n, out_e);

        // node = L edge  (pull into nodes[k] slot; h is dead)
        k_pull<<<(NN + 3) / 4, 256, 0, stream>>>(row_ptr, adj, dinv, out_e, out_n);

        // softmax -> fc1 -> fusion gate; x_new in place into nodes[k]
        k_row<<<2048, 256, 0, stream>>>(out_n, xk, fc1W, fusW, l1b, l2w, l2b, out_n);
    }
}

// Round 5
// 3701.789 us; speedup vs baseline: 4.3666x; 1.4016x over previous
//
#include <hip/hip_runtime.h>
#include <hip/hip_bf16.h>

#define NU_ 50000
#define NI_ 50000
#define NN  (NU_ + NI_)   // 100000
#define DD  64
#define KK  4
#define EE  1000000

// ---------- histogram of node degrees (int counts) ----------
__global__ void k_hist(const int* __restrict__ r, const int* __restrict__ c,
                       int* __restrict__ cnt) {
    int e = blockIdx.x * blockDim.x + threadIdx.x;
    if (e >= EE) return;
    int a = r[e], b = c[e];
    if ((unsigned)a >= (unsigned)NU_ || (unsigned)b >= (unsigned)NI_) return; // defensive
    atomicAdd(&cnt[a], 1);
    atomicAdd(&cnt[NU_ + b], 1);
}

// ---------- single-block exclusive scan of cnt -> row_ptr, cursor; dinv ----------
__global__ __launch_bounds__(1024) void k_scan(const int* __restrict__ cnt,
                                               int* __restrict__ row_ptr,
                                               int* __restrict__ cursor,
                                               float* __restrict__ dinv) {
    __shared__ int sums[1024];
    const int tid = threadIdx.x;
    const int CH = (NN + 1023) / 1024;  // 98
    int begin = tid * CH;
    int end = begin + CH; if (end > NN) end = NN;
    int s = 0;
    for (int i = begin; i < end; i++) s += cnt[i];
    sums[tid] = s;
    __syncthreads();
    for (int off = 1; off < 1024; off <<= 1) {
        int v = (tid >= off) ? sums[tid - off] : 0;
        __syncthreads();
        sums[tid] += v;
        __syncthreads();
    }
    int prefix = (tid > 0) ? sums[tid - 1] : 0;
    for (int i = begin; i < end; i++) {
        row_ptr[i] = prefix;
        cursor[i] = prefix;
        dinv[i] = rsqrtf((float)cnt[i] + 1e-7f);
        prefix += cnt[i];
    }
    if (tid == 1023) row_ptr[NN] = sums[1023];
}

// ---------- scatter edges into CSR adjacency (both directions) ----------
__global__ void k_scatter(const int* __restrict__ r, const int* __restrict__ c,
                          int* __restrict__ cursor, int* __restrict__ adj) {
    int e = blockIdx.x * blockDim.x + threadIdx.x;
    if (e >= EE) return;
    int a = r[e], b = c[e];
    if ((unsigned)a >= (unsigned)NU_ || (unsigned)b >= (unsigned)NI_) return; // defensive
    b += NU_;
    int p = atomicAdd(&cursor[a], 1);
    adj[p] = b;
    int q = atomicAdd(&cursor[b], 1);
    adj[q] = a;
}

// ---------- h = relu(x) + bias (fp32) ----------
__global__ void k_h(const float* __restrict__ x, const float* __restrict__ bias,
                    float* __restrict__ h) {
    int i = blockIdx.x * blockDim.x + threadIdx.x;
    if (i < NN * DD) {
        h[i] = fmaxf(x[i], 0.0f) + bias[i & 63];
    }
}

// ---------- pull-based SpMM: out[row] = dinv[row] * sum_nbr dinv[nbr]*hin[nbr] ----------
__global__ __launch_bounds__(256) void k_pull(const int* __restrict__ row_ptr,
                                              const int* __restrict__ adj,
                                              const float* __restrict__ dinv,
                                              const float* __restrict__ hin,
                                              float* __restrict__ out) {
    const int wave = threadIdx.x >> 6;
    const int lane = threadIdx.x & 63;
    const int row = blockIdx.x * 4 + wave;
    if (row >= NN) return;
    const int start = row_ptr[row];
    const int end = row_ptr[row + 1];
    float acc = 0.0f;
    for (int base = start; base < end; base += 64) {
        int n = end - base; if (n > 64) n = 64;
        int idx = (lane < n) ? adj[base + lane] : 0;
        float dn = (lane < n) ? dinv[idx] : 0.0f;
        #pragma unroll 4
        for (int j = 0; j < n; j++) {
            int nbr = __shfl(idx, j);
            float w = __shfl(dn, j);
            acc = fmaf(w, hin[(size_t)nbr * DD + lane], acc);
        }
    }
    out[(size_t)row * DD + lane] = dinv[row] * acc;
}

// ---------- fused: softmax(node) -> fc1 -> fusion gate -> x_new ----------
// NO LDS: lane j holds fc1W[j][:] and fusW[j][:] in VGPRs; input broadcasts
// via v_readlane (VALU pipe). Runs IN PLACE (node may alias out_nodes).
#define BC(v, d) __uint_as_float(__builtin_amdgcn_readlane(__float_as_uint(v), (d)))

__global__ __launch_bounds__(256) void k_row(
    const float* __restrict__ node, const float* __restrict__ xsrc,
    const float* __restrict__ fc1W, const float* __restrict__ fusW,
    const float* __restrict__ l1b, const float* __restrict__ l2w,
    const float* __restrict__ l2b, float* __restrict__ out_nodes) {
    const int wave = threadIdx.x >> 6;
    const int lane = threadIdx.x & 63;

    // per-lane weight rows (128 VGPRs), loaded once per thread
    float wf[DD], wu[DD];
    #pragma unroll
    for (int d = 0; d < DD; d += 4) {
        *(float4*)&wf[d] = *(const float4*)&fc1W[(size_t)lane * DD + d];
        *(float4*)&wu[d] = *(const float4*)&fusW[(size_t)lane * DD + d];
    }
    const float b1v = l1b[lane];
    const float l2v = l2w[lane];
    const float b2v = l2b[0];

    for (int row = blockIdx.x * 4 + wave; row < NN; row += gridDim.x * 4) {
        const size_t base = (size_t)row * DD + lane;
        float v = node[base];
        // --- softmax over D=64 ---
        float m = v;
        #pragma unroll
        for (int s = 1; s < 64; s <<= 1) m = fmaxf(m, __shfl_xor(m, s));
        float ev = __expf(v - m);
        float sum = ev;
        #pragma unroll
        for (int s = 1; s < 64; s <<= 1) sum += __shfl_xor(sum, s);
        float sm = ev / sum;
        // --- fc1: nf[lane] = sum_d sm[d] * fc1W[lane][d] ---
        float n0 = 0, n1 = 0, n2 = 0, n3 = 0;
        #pragma unroll
        for (int d = 0; d < DD; d += 4) {
            n0 = fmaf(BC(sm, d),     wf[d],     n0);
            n1 = fmaf(BC(sm, d + 1), wf[d + 1], n1);
            n2 = fmaf(BC(sm, d + 2), wf[d + 2], n2);
            n3 = fmaf(BC(sm, d + 3), wf[d + 3], n3);
        }
        float nf = (n0 + n1) + (n2 + n3);
        float xc = xsrc[base];
        // --- fusion branch: xc @ fusW^T ---
        float a0 = 0, a1 = 0, a2 = 0, a3 = 0;
        #pragma unroll
        for (int d = 0; d < DD; d += 4) {
            a0 = fmaf(BC(xc, d),     wu[d],     a0);
            a1 = fmaf(BC(xc, d + 1), wu[d + 1], a1);
            a2 = fmaf(BC(xc, d + 2), wu[d + 2], a2);
            a3 = fmaf(BC(xc, d + 3), wu[d + 3], a3);
        }
        float tt = tanhf(((a0 + a1) + (a2 + a3)) + b1v);
        float p = tt * l2v;
        #pragma unroll
        for (int s = 1; s < 64; s <<= 1) p += __shfl_xor(p, s);
        float s_x = p + b2v;
        // --- fusion branch: nf @ fusW^T ---
        a0 = 0; a1 = 0; a2 = 0; a3 = 0;
        #pragma unroll
        for (int d = 0; d < DD; d += 4) {
            a0 = fmaf(BC(nf, d),     wu[d],     a0);
            a1 = fmaf(BC(nf, d + 1), wu[d + 1], a1);
            a2 = fmaf(BC(nf, d + 2), wu[d + 2], a2);
            a3 = fmaf(BC(nf, d + 3), wu[d + 3], a3);
        }
        tt = tanhf(((a0 + a1) + (a2 + a3)) + b1v);
        p = tt * l2v;
        #pragma unroll
        for (int s = 1; s < 64; s <<= 1) p += __shfl_xor(p, s);
        float s_n = p + b2v;
        // --- 2-way softmax gate + blend ---
        float mm = fmaxf(s_x, s_n);
        float e0 = __expf(s_x - mm), e1 = __expf(s_n - mm);
        float inv = 1.0f / (e0 + e1);
        float xn = (e0 * xc + e1 * nf) * inv;
        out_nodes[base] = xn;
    }
}

extern "C" void kernel_launch(void* const* d_in, const int* in_sizes, int n_in,
                              void* d_out, int out_size, void* d_ws, size_t ws_size,
                              hipStream_t stream) {
    const float* x    = (const float*)d_in[0];
    const float* b1   = (const float*)d_in[1];  // hgc1_bias
    const float* fc1W = (const float*)d_in[2];
    const float* fusW = (const float*)d_in[3];  // fus_l1_W
    const float* l1b  = (const float*)d_in[4];
    const float* l2w  = (const float*)d_in[5];
    const float* l2b  = (const float*)d_in[6];
    const int* rows = (const int*)d_in[7];
    const int* cols = (const int*)d_in[8];
    float* out = (float*)d_out;

    const int ND = NN * DD;  // 6,400,000

    // workspace layout (~9.7 MB)
    float* dinv    = (float*)d_ws;           // NN
    int*   cnt     = (int*)(dinv + NN);      // NN
    int*   row_ptr = cnt + NN;               // NN+1
    int*   cursor  = row_ptr + NN + 1;       // NN
    int*   adj     = cursor + NN;            // 2*EE

    for (int k = 0; k < KK; k++) {
        const int* r = rows + (size_t)k * EE;
        const int* c = cols + (size_t)k * EE;
        const float* xk = (k == 0) ? x : out + (size_t)(k - 1) * ND;  // carry
        float* out_n = out + (size_t)k * ND;         // nodes[k] slot
        float* out_e = out + (size_t)(KK + k) * ND;  // edges[k] slot

        // --- CSR build ---
        hipMemsetAsync(cnt, 0, NN * sizeof(int), stream);
        k_hist<<<(EE + 255) / 256, 256, 0, stream>>>(r, c, cnt);
        k_scan<<<1, 1024, 0, stream>>>(cnt, row_ptr, cursor, dinv);
        k_scatter<<<(EE + 255) / 256, 256, 0, stream>>>(r, c, cursor, adj);

        // h = relu(xk)+bias, staged in nodes[k] slot
        k_h<<<(ND + 255) / 256, 256, 0, stream>>>(xk, b1, out_n);

        // edge = L h  (pull, direct store into edges[k] output)
        k_pull<<<(NN + 3) / 4, 256, 0, stream>>>(row_ptr, adj, dinv, out_n, out_e);

        // node = L edge  (pull into nodes[k] slot; h is dead)
        k_pull<<<(NN + 3) / 4, 256, 0, stream>>>(row_ptr, adj, dinv, out_e, out_n);

        // softmax -> fc1 -> fusion gate; x_new in place into nodes[k]
        k_row<<<1024, 256, 0, stream>>>(out_n, xk, fc1W, fusW, l1b, l2w, l2b, out_n);
    }
}

// Round 6
// 2603.732 us; speedup vs baseline: 6.2080x; 1.4217x over previous
//
#include <hip/hip_runtime.h>
#include <hip/hip_bf16.h>

#define NU_ 50000
#define NI_ 50000
#define NN  (NU_ + NI_)   // 100000
#define DD  64
#define KK  4
#define EE  1000000
#define SCAN_B ((NN + 255) / 256)   // 391

// ---------- histogram of node degrees (int counts) ----------
__global__ void k_hist(const int* __restrict__ r, const int* __restrict__ c,
                       int* __restrict__ cnt) {
    int e = blockIdx.x * blockDim.x + threadIdx.x;
    if (e >= EE) return;
    int a = r[e], b = c[e];
    if ((unsigned)a >= (unsigned)NU_ || (unsigned)b >= (unsigned)NI_) return; // defensive
    atomicAdd(&cnt[a], 1);
    atomicAdd(&cnt[NU_ + b], 1);
}

// ---------- pass 1: per-block sums of cnt ----------
__global__ __launch_bounds__(256) void k_bsum(const int* __restrict__ cnt,
                                              int* __restrict__ bsum) {
    __shared__ int s[256];
    int i = blockIdx.x * 256 + threadIdx.x;
    s[threadIdx.x] = (i < NN) ? cnt[i] : 0;
    __syncthreads();
    #pragma unroll
    for (int off = 128; off > 0; off >>= 1) {
        if (threadIdx.x < off) s[threadIdx.x] += s[threadIdx.x + off];
        __syncthreads();
    }
    if (threadIdx.x == 0) bsum[blockIdx.x] = s[0];
}

// ---------- pass 2: scan 391 block sums (one small block) ----------
__global__ __launch_bounds__(512) void k_sscan(const int* __restrict__ bsum,
                                               int* __restrict__ bofs) {
    __shared__ int s[512];
    int tid = threadIdx.x;
    s[tid] = (tid < SCAN_B) ? bsum[tid] : 0;
    __syncthreads();
    #pragma unroll
    for (int off = 1; off < 512; off <<= 1) {
        int v = (tid >= off) ? s[tid - off] : 0;
        __syncthreads();
        s[tid] += v;
        __syncthreads();
    }
    if (tid < SCAN_B) bofs[tid] = (tid > 0) ? s[tid - 1] : 0;
}

// ---------- pass 3: intra-block scan + offset -> row_ptr/cursor/dinv ----------
__global__ __launch_bounds__(256) void k_apply(const int* __restrict__ cnt,
                                               const int* __restrict__ bofs,
                                               int* __restrict__ row_ptr,
                                               int* __restrict__ cursor,
                                               float* __restrict__ dinv) {
    __shared__ int s[256];
    int i = blockIdx.x * 256 + threadIdx.x;
    int v = (i < NN) ? cnt[i] : 0;
    s[threadIdx.x] = v;
    __syncthreads();
    #pragma unroll
    for (int off = 1; off < 256; off <<= 1) {
        int t = (threadIdx.x >= off) ? s[threadIdx.x - off] : 0;
        __syncthreads();
        s[threadIdx.x] += t;
        __syncthreads();
    }
    if (i < NN) {
        int incl = s[threadIdx.x] + bofs[blockIdx.x];
        int excl = incl - v;
        row_ptr[i] = excl;
        cursor[i] = excl;
        dinv[i] = rsqrtf((float)v + 1e-7f);
        if (i == NN - 1) row_ptr[NN] = incl;
    }
}

// ---------- scatter edges into CSR adjacency (both directions) ----------
__global__ void k_scatter(const int* __restrict__ r, const int* __restrict__ c,
                          int* __restrict__ cursor, int* __restrict__ adj) {
    int e = blockIdx.x * blockDim.x + threadIdx.x;
    if (e >= EE) return;
    int a = r[e], b = c[e];
    if ((unsigned)a >= (unsigned)NU_ || (unsigned)b >= (unsigned)NI_) return; // defensive
    b += NU_;
    int p = atomicAdd(&cursor[a], 1);
    adj[p] = b;
    int q = atomicAdd(&cursor[b], 1);
    adj[q] = a;
}

// ---------- pull SpMM with fused h = relu(x)+bias on the gathered operand ----------
// out[row] = dinv[row] * sum_nbr dinv[nbr] * (relu(x[nbr]) + bias)
__global__ __launch_bounds__(256) void k_pull_h(const int* __restrict__ row_ptr,
                                                const int* __restrict__ adj,
                                                const float* __restrict__ dinv,
                                                const float* __restrict__ x,
                                                const float* __restrict__ bias,
                                                float* __restrict__ out) {
    const int wave = threadIdx.x >> 6;
    const int lane = threadIdx.x & 63;
    const int row = blockIdx.x * 4 + wave;
    if (row >= NN) return;
    const float bv = bias[lane];
    const int start = row_ptr[row];
    const int end = row_ptr[row + 1];
    float acc = 0.0f;
    for (int base = start; base < end; base += 64) {
        int n = end - base; if (n > 64) n = 64;
        int idx = (lane < n) ? adj[base + lane] : 0;
        float dn = (lane < n) ? dinv[idx] : 0.0f;
        #pragma unroll 4
        for (int j = 0; j < n; j++) {
            int nbr = __shfl(idx, j);
            float w = __shfl(dn, j);
            float xv = x[(size_t)nbr * DD + lane];
            acc = fmaf(w, fmaxf(xv, 0.0f) + bv, acc);
        }
    }
    out[(size_t)row * DD + lane] = dinv[row] * acc;
}

// ---------- plain pull SpMM ----------
__global__ __launch_bounds__(256) void k_pull(const int* __restrict__ row_ptr,
                                              const int* __restrict__ adj,
                                              const float* __restrict__ dinv,
                                              const float* __restrict__ hin,
                                              float* __restrict__ out) {
    const int wave = threadIdx.x >> 6;
    const int lane = threadIdx.x & 63;
    const int row = blockIdx.x * 4 + wave;
    if (row >= NN) return;
    const int start = row_ptr[row];
    const int end = row_ptr[row + 1];
    float acc = 0.0f;
    for (int base = start; base < end; base += 64) {
        int n = end - base; if (n > 64) n = 64;
        int idx = (lane < n) ? adj[base + lane] : 0;
        float dn = (lane < n) ? dinv[idx] : 0.0f;
        #pragma unroll 4
        for (int j = 0; j < n; j++) {
            int nbr = __shfl(idx, j);
            float w = __shfl(dn, j);
            acc = fmaf(w, hin[(size_t)nbr * DD + lane], acc);
        }
    }
    out[(size_t)row * DD + lane] = dinv[row] * acc;
}

// ---------- fused: softmax(node) -> fc1 -> fusion gate -> x_new ----------
// NO LDS: lane j holds fc1W[j][:] and fusW[j][:] in VGPRs; broadcasts via
// v_readlane (VALU pipe). Runs IN PLACE (node may alias out_nodes).
#define BC(v, d) __uint_as_float(__builtin_amdgcn_readlane(__float_as_uint(v), (d)))

__global__ __launch_bounds__(256) void k_row(
    const float* __restrict__ node, const float* __restrict__ xsrc,
    const float* __restrict__ fc1W, const float* __restrict__ fusW,
    const float* __restrict__ l1b, const float* __restrict__ l2w,
    const float* __restrict__ l2b, float* __restrict__ out_nodes) {
    const int wave = threadIdx.x >> 6;
    const int lane = threadIdx.x & 63;

    float wf[DD], wu[DD];
    #pragma unroll
    for (int d = 0; d < DD; d += 4) {
        *(float4*)&wf[d] = *(const float4*)&fc1W[(size_t)lane * DD + d];
        *(float4*)&wu[d] = *(const float4*)&fusW[(size_t)lane * DD + d];
    }
    const float b1v = l1b[lane];
    const float l2v = l2w[lane];
    const float b2v = l2b[0];

    for (int row = blockIdx.x * 4 + wave; row < NN; row += gridDim.x * 4) {
        const size_t base = (size_t)row * DD + lane;
        float v = node[base];
        // --- softmax over D=64 ---
        float m = v;
        #pragma unroll
        for (int s = 1; s < 64; s <<= 1) m = fmaxf(m, __shfl_xor(m, s));
        float ev = __expf(v - m);
        float sum = ev;
        #pragma unroll
        for (int s = 1; s < 64; s <<= 1) sum += __shfl_xor(sum, s);
        float sm = ev / sum;
        // --- fc1 ---
        float n0 = 0, n1 = 0, n2 = 0, n3 = 0;
        #pragma unroll
        for (int d = 0; d < DD; d += 4) {
            n0 = fmaf(BC(sm, d),     wf[d],     n0);
            n1 = fmaf(BC(sm, d + 1), wf[d + 1], n1);
            n2 = fmaf(BC(sm, d + 2), wf[d + 2], n2);
            n3 = fmaf(BC(sm, d + 3), wf[d + 3], n3);
        }
        float nf = (n0 + n1) + (n2 + n3);
        float xc = xsrc[base];
        // --- fusion branch: xc ---
        float a0 = 0, a1 = 0, a2 = 0, a3 = 0;
        #pragma unroll
        for (int d = 0; d < DD; d += 4) {
            a0 = fmaf(BC(xc, d),     wu[d],     a0);
            a1 = fmaf(BC(xc, d + 1), wu[d + 1], a1);
            a2 = fmaf(BC(xc, d + 2), wu[d + 2], a2);
            a3 = fmaf(BC(xc, d + 3), wu[d + 3], a3);
        }
        float tt = tanhf(((a0 + a1) + (a2 + a3)) + b1v);
        float p = tt * l2v;
        #pragma unroll
        for (int s = 1; s < 64; s <<= 1) p += __shfl_xor(p, s);
        float s_x = p + b2v;
        // --- fusion branch: nf ---
        a0 = 0; a1 = 0; a2 = 0; a3 = 0;
        #pragma unroll
        for (int d = 0; d < DD; d += 4) {
            a0 = fmaf(BC(nf, d),     wu[d],     a0);
            a1 = fmaf(BC(nf, d + 1), wu[d + 1], a1);
            a2 = fmaf(BC(nf, d + 2), wu[d + 2], a2);
            a3 = fmaf(BC(nf, d + 3), wu[d + 3], a3);
        }
        tt = tanhf(((a0 + a1) + (a2 + a3)) + b1v);
        p = tt * l2v;
        #pragma unroll
        for (int s = 1; s < 64; s <<= 1) p += __shfl_xor(p, s);
        float s_n = p + b2v;
        // --- gate + blend ---
        float mm = fmaxf(s_x, s_n);
        float e0 = __expf(s_x - mm), e1 = __expf(s_n - mm);
        float inv = 1.0f / (e0 + e1);
        float xn = (e0 * xc + e1 * nf) * inv;
        out_nodes[base] = xn;
    }
}

extern "C" void kernel_launch(void* const* d_in, const int* in_sizes, int n_in,
                              void* d_out, int out_size, void* d_ws, size_t ws_size,
                              hipStream_t stream) {
    const float* x    = (const float*)d_in[0];
    const float* b1   = (const float*)d_in[1];  // hgc1_bias
    const float* fc1W = (const float*)d_in[2];
    const float* fusW = (const float*)d_in[3];  // fus_l1_W
    const float* l1b  = (const float*)d_in[4];
    const float* l2w  = (const float*)d_in[5];
    const float* l2b  = (const float*)d_in[6];
    const int* rows = (const int*)d_in[7];
    const int* cols = (const int*)d_in[8];
    float* out = (float*)d_out;

    const int ND = NN * DD;  // 6,400,000

    // workspace layout (~9.7 MB)
    float* dinv    = (float*)d_ws;           // NN
    int*   cnt     = (int*)(dinv + NN);      // NN
    int*   row_ptr = cnt + NN;               // NN+1
    int*   cursor  = row_ptr + NN + 1;       // NN
    int*   bsum    = cursor + NN;            // SCAN_B
    int*   bofs    = bsum + SCAN_B;          // SCAN_B
    int*   adj     = bofs + SCAN_B;          // 2*EE

    for (int k = 0; k < KK; k++) {
        const int* r = rows + (size_t)k * EE;
        const int* c = cols + (size_t)k * EE;
        const float* xk = (k == 0) ? x : out + (size_t)(k - 1) * ND;  // carry
        float* out_n = out + (size_t)k * ND;         // nodes[k] slot
        float* out_e = out + (size_t)(KK + k) * ND;  // edges[k] slot

        // --- CSR build (parallel scan) ---
        hipMemsetAsync(cnt, 0, NN * sizeof(int), stream);
        k_hist<<<(EE + 255) / 256, 256, 0, stream>>>(r, c, cnt);
        k_bsum<<<SCAN_B, 256, 0, stream>>>(cnt, bsum);
        k_sscan<<<1, 512, 0, stream>>>(bsum, bofs);
        k_apply<<<SCAN_B, 256, 0, stream>>>(cnt, bofs, row_ptr, cursor, dinv);
        k_scatter<<<(EE + 255) / 256, 256, 0, stream>>>(r, c, cursor, adj);

        // edge = L (relu(xk)+bias)   (fused h, direct store into edges[k])
        k_pull_h<<<(NN + 3) / 4, 256, 0, stream>>>(row_ptr, adj, dinv, xk, b1, out_e);

        // node = L edge  (into nodes[k] slot)
        k_pull<<<(NN + 3) / 4, 256, 0, stream>>>(row_ptr, adj, dinv, out_e, out_n);

        // softmax -> fc1 -> fusion gate; x_new in place into nodes[k]
        k_row<<<1024, 256, 0, stream>>>(out_n, xk, fc1W, fusW, l1b, l2w, l2b, out_n);
    }
}